// Round 1
// baseline (2178.896 us; speedup 1.0000x reference)
//
#include <hip/hip_runtime.h>
#include <stdint.h>

#define T_STEPS 512
#define BATCH   4096
#define DIN     64
#define HID     70
#define G4      280      // 4*HID
#define KDIM    160      // padded K per layer (5 k-steps of 32)
#define KS      5
#define RB      16       // batch rows per block
#define WAVES   6
#define NTHR    (WAVES*64)

typedef __bf16 bf16x8 __attribute__((ext_vector_type(8)));
typedef float  f32x4  __attribute__((ext_vector_type(4)));
typedef unsigned short ushort_t;
typedef ushort_t us8 __attribute__((ext_vector_type(8)));

union BU { us8 u; bf16x8 b; };

__device__ __forceinline__ ushort_t f2bf(float f) {
    uint32_t u = __float_as_uint(f);
    u += 0x7fffu + ((u >> 16) & 1u);   // round-to-nearest-even
    return (ushort_t)(u >> 16);
}
__device__ __forceinline__ float sigmoidf_(float x) {
    return __fdividef(1.0f, 1.0f + __expf(-x));
}
__device__ __forceinline__ float tanhf_(float x) {
    x = fminf(fmaxf(x, -30.f), 30.f);
    float e = __expf(2.0f * x);
    return __fdividef(e - 1.0f, e + 1.0f);
}

// Build padded bf16 weight layouts + summed biases in workspace.
// W0p[288][160]: k<64 -> W_ih0[g][k]; 64<=k<134 -> W_hh0[g][k-64]; else 0
// W1p[288][160]: k<70 -> W_ih1[g][k]; 80<=k<150 -> W_hh1[g][k-80]; else 0
__global__ void prep_kernel(const float* __restrict__ Wih0, const float* __restrict__ Whh0,
                            const float* __restrict__ bih0, const float* __restrict__ bhh0,
                            const float* __restrict__ Wih1, const float* __restrict__ Whh1,
                            const float* __restrict__ bih1, const float* __restrict__ bhh1,
                            ushort_t* __restrict__ W0p, ushort_t* __restrict__ W1p,
                            float* __restrict__ bsum0, float* __restrict__ bsum1) {
    int idx = blockIdx.x * 256 + threadIdx.x;
    const int n = 288 * KDIM;
    if (idx < n) {
        int g = idx / KDIM, k = idx - g * KDIM;
        float v0 = 0.f, v1 = 0.f;
        if (g < G4) {
            if (k < 64)        v0 = Wih0[g*64 + k];
            else if (k < 134)  v0 = Whh0[g*70 + (k-64)];
            if (k < 70)                 v1 = Wih1[g*70 + k];
            else if (k >= 80 && k < 150) v1 = Whh1[g*70 + (k-80)];
        }
        W0p[idx] = f2bf(v0);
        W1p[idx] = f2bf(v1);
    }
    if (idx < 288) {
        float s0 = 0.f, s1 = 0.f;
        if (idx < G4) { s0 = bih0[idx] + bhh0[idx]; s1 = bih1[idx] + bhh1[idx]; }
        bsum0[idx] = s0; bsum1[idx] = s1;
    }
}

__global__ __launch_bounds__(NTHR) void lstm_kernel(
    const float* __restrict__ x,              // [T][B][64] fp32
    const ushort_t* __restrict__ W0p, const ushort_t* __restrict__ W1p,
    const float* __restrict__ bsum0, const float* __restrict__ bsum1,
    const float* __restrict__ W1h, const float* __restrict__ b1h,
    const float* __restrict__ W2h, const float* __restrict__ b2h,
    float* __restrict__ out)
{
    constexpr int A0S = 104;   // LDS stride (shorts): 70 h0 + pad (bank-spread, 16B aligned)
    constexpr int A1S = 168;   // 160 cols ([h0|pad|h1|pad]) + pad
    constexpr int GS  = 292;   // gate buffer stride (floats)
    __shared__ ushort_t A0[RB*A0S];      // layer0 A h-part: h0 padded to 96 cols
    __shared__ ushort_t A1[RB*A1S];      // layer1 A: h0 (0..70), pad, h1 (80..150), pad
    __shared__ float    gates[RB*GS];
    __shared__ float    h1f[RB*HID];
    __shared__ float    mid[RB*50];

    const int tid  = threadIdx.x;
    const int wave = tid >> 6;
    const int lane = tid & 63;
    const int n15  = lane & 15;
    const int q    = lane >> 4;
    const int blk  = blockIdx.x;

    // zero h-state (h(-1)=0) and all pads
    for (int i = tid; i < RB*A0S; i += NTHR) A0[i] = 0;
    for (int i = tid; i < RB*A1S; i += NTHR) A1[i] = 0;

    // Register-resident weight B-fragments.
    // Wave w owns layer0 n-tiles {w, w+6, w+12} (wf[0..2]) and same layer1 n-tiles (wf[3..5]).
    bf16x8 wf[6][KS];
    float  wb[6];
    #pragma unroll
    for (int j = 0; j < 3; j++) {
        const int nt = wave + 6*j;
        const int gro = (nt*16 + n15) * KDIM + q*8;
        #pragma unroll
        for (int ks = 0; ks < KS; ks++) {
            wf[j][ks]   = *(const bf16x8*)(W0p + gro + ks*32);
            wf[3+j][ks] = *(const bf16x8*)(W1p + gro + ks*32);
        }
        wb[j]   = bsum0[nt*16 + n15];
        wb[3+j] = bsum1[nt*16 + n15];
    }

    float c0[3] = {0.f,0.f,0.f}, c1[3] = {0.f,0.f,0.f};

    // x A-fragment source: lane supplies row m=n15, k = q*8+j (+32 for kstep 1)
    const float* xbase = x + ((size_t)blk*RB + n15) * DIN + q*8;
    f32x4 xc[4], xn[4];
    {
        const float* p = xbase;
        xc[0] = *(const f32x4*)(p);      xc[1] = *(const f32x4*)(p+4);
        xc[2] = *(const f32x4*)(p+32);   xc[3] = *(const f32x4*)(p+36);
    }
    __syncthreads();

    for (int t = 0; t < T_STEPS; t++) {
        // prefetch x(t+1) into registers (hides HBM latency across the step)
        {
            const int tn = (t+1 < T_STEPS) ? t+1 : t;
            const float* p = xbase + (size_t)tn * (BATCH*DIN);
            xn[0] = *(const f32x4*)(p);      xn[1] = *(const f32x4*)(p+4);
            xn[2] = *(const f32x4*)(p+32);   xn[3] = *(const f32x4*)(p+36);
        }
        // ---- phase 1: layer0 MFMA ----
        BU ax0, ax1;
        #pragma unroll
        for (int e = 0; e < 4; e++) {
            ax0.u[e]   = f2bf(xc[0][e]);  ax0.u[4+e] = f2bf(xc[1][e]);
            ax1.u[e]   = f2bf(xc[2][e]);  ax1.u[4+e] = f2bf(xc[3][e]);
        }
        bf16x8 ah[3];
        #pragma unroll
        for (int i = 0; i < 3; i++)
            ah[i] = *(const bf16x8*)(A0 + n15*A0S + i*32 + q*8);
        #pragma unroll
        for (int j = 0; j < 3; j++) {
            f32x4 acc = { wb[j], wb[j], wb[j], wb[j] };
            acc = __builtin_amdgcn_mfma_f32_16x16x32_bf16(ax0.b, wf[j][0], acc, 0,0,0);
            acc = __builtin_amdgcn_mfma_f32_16x16x32_bf16(ax1.b, wf[j][1], acc, 0,0,0);
            acc = __builtin_amdgcn_mfma_f32_16x16x32_bf16(ah[0], wf[j][2], acc, 0,0,0);
            acc = __builtin_amdgcn_mfma_f32_16x16x32_bf16(ah[1], wf[j][3], acc, 0,0,0);
            acc = __builtin_amdgcn_mfma_f32_16x16x32_bf16(ah[2], wf[j][4], acc, 0,0,0);
            const int base = (wave + 6*j)*16 + n15;
            #pragma unroll
            for (int r = 0; r < 4; r++) gates[(q*4+r)*GS + base] = acc[r];
        }
        __syncthreads();
        // ---- phase 2: layer0 elementwise (c0 in regs) ----
        #pragma unroll
        for (int kk = 0; kk < 3; kk++) {
            const int u = tid + kk*NTHR;
            if (u < RB*HID) {
                const int r = u / HID, h = u - r*HID;
                const float* gr = gates + r*GS;
                float gi = gr[h], gf = gr[70+h], gg = gr[140+h], go = gr[210+h];
                float cn = sigmoidf_(gf)*c0[kk] + sigmoidf_(gi)*tanhf_(gg);
                c0[kk] = cn;
                float hv = sigmoidf_(go)*tanhf_(cn);
                ushort_t hb = f2bf(hv);
                A0[r*A0S + h] = hb;       // for next step's layer0
                A1[r*A1S + h] = hb;       // layer1 input, this step
            }
        }
        __syncthreads();
        // ---- phase 3: layer1 MFMA ----
        bf16x8 a1[KS];
        #pragma unroll
        for (int ks = 0; ks < KS; ks++)
            a1[ks] = *(const bf16x8*)(A1 + n15*A1S + ks*32 + q*8);
        #pragma unroll
        for (int j = 0; j < 3; j++) {
            f32x4 acc = { wb[3+j], wb[3+j], wb[3+j], wb[3+j] };
            #pragma unroll
            for (int ks = 0; ks < KS; ks++)
                acc = __builtin_amdgcn_mfma_f32_16x16x32_bf16(a1[ks], wf[3+j][ks], acc, 0,0,0);
            const int base = (wave + 6*j)*16 + n15;
            #pragma unroll
            for (int r = 0; r < 4; r++) gates[(q*4+r)*GS + base] = acc[r];
        }
        __syncthreads();
        // ---- phase 4: layer1 elementwise (c1 in regs) ----
        #pragma unroll
        for (int kk = 0; kk < 3; kk++) {
            const int u = tid + kk*NTHR;
            if (u < RB*HID) {
                const int r = u / HID, h = u - r*HID;
                const float* gr = gates + r*GS;
                float gi = gr[h], gf = gr[70+h], gg = gr[140+h], go = gr[210+h];
                float cn = sigmoidf_(gf)*c1[kk] + sigmoidf_(gi)*tanhf_(gg);
                c1[kk] = cn;
                float hv = sigmoidf_(go)*tanhf_(cn);
                A1[r*A1S + 80 + h] = f2bf(hv);      // recurrent h1
                if (t == T_STEPS-1) h1f[r*HID + h] = hv;  // fp32 copy for head
            }
        }
        __syncthreads();
        xc[0]=xn[0]; xc[1]=xn[1]; xc[2]=xn[2]; xc[3]=xn[3];
    }

    // ---- head: out = sigmoid(W2 @ relu(W1 @ h1 + b1) + b2) ----
    for (int uu = tid; uu < RB*50; uu += NTHR) {
        const int r = uu / 50, j = uu - r*50;
        float s = b1h[j];
        const float* w  = W1h + j*HID;
        const float* hh = h1f + r*HID;
        #pragma unroll 7
        for (int h = 0; h < HID; h++) s += w[h]*hh[h];
        mid[uu] = fmaxf(s, 0.0f);
    }
    __syncthreads();
    if (tid < RB) {
        float s = b2h[0];
        const float* m = mid + tid*50;
        #pragma unroll 10
        for (int j = 0; j < 50; j++) s += W2h[j]*m[j];
        out[blk*RB + tid] = sigmoidf_(s);
    }
}

extern "C" void kernel_launch(void* const* d_in, const int* in_sizes, int n_in,
                              void* d_out, int out_size, void* d_ws, size_t ws_size,
                              hipStream_t stream) {
    (void)in_sizes; (void)n_in; (void)out_size; (void)ws_size;
    const float* x    = (const float*)d_in[0];
    const float* Wih0 = (const float*)d_in[2];
    const float* Whh0 = (const float*)d_in[3];
    const float* bih0 = (const float*)d_in[4];
    const float* bhh0 = (const float*)d_in[5];
    const float* Wih1 = (const float*)d_in[6];
    const float* Whh1 = (const float*)d_in[7];
    const float* bih1 = (const float*)d_in[8];
    const float* bhh1 = (const float*)d_in[9];
    const float* W1h  = (const float*)d_in[10];
    const float* b1h  = (const float*)d_in[11];
    const float* W2h  = (const float*)d_in[12];
    const float* b2h  = (const float*)d_in[13];

    char* ws = (char*)d_ws;
    ushort_t* W0p  = (ushort_t*)ws;                       // 288*160 bf16 = 92160 B
    ushort_t* W1p  = (ushort_t*)(ws + 92160);             // 92160 B
    float*    bs0  = (float*)(ws + 184320);               // 288 f32
    float*    bs1  = (float*)(ws + 184320 + 1152);

    prep_kernel<<<180, 256, 0, stream>>>(Wih0, Whh0, bih0, bhh0,
                                         Wih1, Whh1, bih1, bhh1,
                                         W0p, W1p, bs0, bs1);
    lstm_kernel<<<BATCH/RB, NTHR, 0, stream>>>(x, W0p, W1p, bs0, bs1,
                                               W1h, b1h, W2h, b2h, (float*)d_out);
}

// Round 2
// 1946.170 us; speedup vs baseline: 1.1196x; 1.1196x over previous
//
#include <hip/hip_runtime.h>
#include <stdint.h>

#define T_STEPS 512
#define BATCH   4096
#define DIN     64
#define HID     70
#define G4      280      // 4*HID
#define KDIM    160      // padded K per layer (5 k-steps of 32)
#define KS      5
#define RB      8        // batch rows per block (512 blocks -> 2 blocks/CU)
#define MR      16       // MFMA M (rows 8..15 are zero padding)
#define WAVES   6
#define NTHR    (WAVES*64)

typedef __bf16 bf16x8 __attribute__((ext_vector_type(8)));
typedef float  f32x4  __attribute__((ext_vector_type(4)));
typedef unsigned short ushort_t;
typedef ushort_t us4 __attribute__((ext_vector_type(4)));

__device__ __forceinline__ ushort_t f2bf(float f) {
    uint32_t u = __float_as_uint(f);
    u += 0x7fffu + ((u >> 16) & 1u);   // round-to-nearest-even
    return (ushort_t)(u >> 16);
}
// 1 v_exp + 1 v_rcp (+1 add, 1 mul) instead of __fdividef's sequence
__device__ __forceinline__ float sigm(float x) {
    return __builtin_amdgcn_rcpf(1.0f + __expf(-x));
}
__device__ __forceinline__ float tanh_(float x) {
    x = fminf(fmaxf(x, -15.f), 15.f);              // avoid inf -> NaN
    float r = __builtin_amdgcn_rcpf(1.0f + __expf(2.0f * x));
    return 1.0f - 2.0f * r;                        // (e-1)/(e+1)
}

// Padded bf16 weight layouts + summed biases in workspace.
// W0p[288][160]: k<64 -> W_ih0[g][k]; 64<=k<134 -> W_hh0[g][k-64]; else 0
// W1p[288][160]: k<70 -> W_ih1[g][k]; 80<=k<150 -> W_hh1[g][k-80]; else 0
__global__ void prep_kernel(const float* __restrict__ Wih0, const float* __restrict__ Whh0,
                            const float* __restrict__ bih0, const float* __restrict__ bhh0,
                            const float* __restrict__ Wih1, const float* __restrict__ Whh1,
                            const float* __restrict__ bih1, const float* __restrict__ bhh1,
                            ushort_t* __restrict__ W0p, ushort_t* __restrict__ W1p,
                            float* __restrict__ bsum0, float* __restrict__ bsum1) {
    int idx = blockIdx.x * 256 + threadIdx.x;
    const int n = 288 * KDIM;
    if (idx < n) {
        int g = idx / KDIM, k = idx - g * KDIM;
        float v0 = 0.f, v1 = 0.f;
        if (g < G4) {
            if (k < 64)        v0 = Wih0[g*64 + k];
            else if (k < 134)  v0 = Whh0[g*70 + (k-64)];
            if (k < 70)                 v1 = Wih1[g*70 + k];
            else if (k >= 80 && k < 150) v1 = Whh1[g*70 + (k-80)];
        }
        W0p[idx] = f2bf(v0);
        W1p[idx] = f2bf(v1);
    }
    if (idx < 288) {
        float s0 = 0.f, s1 = 0.f;
        if (idx < G4) { s0 = bih0[idx] + bhh0[idx]; s1 = bih1[idx] + bhh1[idx]; }
        bsum0[idx] = s0; bsum1[idx] = s1;
    }
}

__global__ __launch_bounds__(NTHR) void lstm_kernel(
    const float* __restrict__ x,              // [T][B][64] fp32
    const ushort_t* __restrict__ W0p, const ushort_t* __restrict__ W1p,
    const float* __restrict__ bsum0, const float* __restrict__ bsum1,
    const float* __restrict__ W1h, const float* __restrict__ b1h,
    const float* __restrict__ W2h, const float* __restrict__ b2h,
    float* __restrict__ out)
{
    constexpr int AS = 168;    // LDS k-panel stride (shorts); 168*2=336B, 16B aligned
    constexpr int GS = 292;    // gate buffer stride (floats)
    // A0 cols: 0..63 x(t) | 64..133 h0(t-1) | 134.. zero
    // A1 cols: 0..69 h0(t) | 70..79 zero | 80..149 h1(t-1) | 150.. zero
    __shared__ alignas(16) ushort_t A0[MR*AS];
    __shared__ alignas(16) ushort_t A1[MR*AS];
    __shared__ float gates[MR*GS];
    __shared__ float h1f[RB*HID];
    __shared__ float mid[RB*50];

    const int tid  = threadIdx.x;
    const int wave = tid >> 6;
    const int lane = tid & 63;
    const int n15  = lane & 15;
    const int q    = lane >> 4;
    const int blk  = blockIdx.x;

    // x staging: 512 floats/block/step, threads 0..127 load f32x4 (2KB coalesced)
    const bool xl = (tid < 128);
    const float* xbase = x + (size_t)blk * (RB*DIN) + tid * 4;
    const int xrow = tid >> 4;           // LDS row for this thread's 4 values
    const int xcol = (tid & 15) * 4;

    // zero h-state / pads (rows 8..15 stay zero forever)
    for (int i = tid; i < MR*AS; i += NTHR) { A0[i] = 0; A1[i] = 0; }

    // Register-resident weight B-fragments.
    // Wave w owns n-tiles {w, w+6, w+12} for both layers.
    bf16x8 wf[6][KS];
    float  wb[6];
    #pragma unroll
    for (int j = 0; j < 3; j++) {
        const int nt = wave + 6*j;
        const int gro = (nt*16 + n15) * KDIM + q*8;
        #pragma unroll
        for (int ks = 0; ks < KS; ks++) {
            wf[j][ks]   = *(const bf16x8*)(W0p + gro + ks*32);
            wf[3+j][ks] = *(const bf16x8*)(W1p + gro + ks*32);
        }
        wb[j]   = bsum0[nt*16 + n15];
        wb[3+j] = bsum1[nt*16 + n15];
    }

    float c0[2] = {0.f, 0.f}, c1[2] = {0.f, 0.f};

    f32x4 xn;
    if (xl) xn = *(const f32x4*)xbase;
    __syncthreads();                    // zeros done
    if (xl) {                           // write x(0)
        us4 s;
        #pragma unroll
        for (int e = 0; e < 4; e++) s[e] = f2bf(xn[e]);
        *(us4*)(A0 + xrow*AS + xcol) = s;
    }
    __syncthreads();

    for (int t = 0; t < T_STEPS; t++) {
        // prefetch x(t+1) into registers; LDS-written in phase 4
        if (xl) {
            const int tn = (t+1 < T_STEPS) ? t+1 : t;
            xn = *(const f32x4*)(xbase + (size_t)tn * (BATCH*DIN));
        }
        // ---- phase 1: layer0 MFMA ----
        {
            bf16x8 a0[KS];
            #pragma unroll
            for (int ks = 0; ks < KS; ks++)
                a0[ks] = *(const bf16x8*)(A0 + n15*AS + ks*32 + q*8);
            #pragma unroll
            for (int j = 0; j < 3; j++) {
                f32x4 acc = { wb[j], wb[j], wb[j], wb[j] };
                #pragma unroll
                for (int ks = 0; ks < KS; ks++)
                    acc = __builtin_amdgcn_mfma_f32_16x16x32_bf16(a0[ks], wf[j][ks], acc, 0,0,0);
                const int base = (wave + 6*j)*16 + n15;
                #pragma unroll
                for (int r = 0; r < 4; r++) gates[(q*4+r)*GS + base] = acc[r];
            }
        }
        __syncthreads();
        // ---- phase 2: layer0 elementwise (c0 in regs) ----
        #pragma unroll
        for (int kk = 0; kk < 2; kk++) {
            const int u = tid + kk*NTHR;
            if (u < RB*HID) {
                const int r = u / HID, h = u - r*HID;
                const float* gr = gates + r*GS;
                float gi = gr[h], gf = gr[70+h], gg = gr[140+h], go = gr[210+h];
                float cn = sigm(gf)*c0[kk] + sigm(gi)*tanh_(gg);
                c0[kk] = cn;
                float hv = sigm(go)*tanh_(cn);
                ushort_t hb = f2bf(hv);
                A0[r*AS + 64 + h] = hb;   // next step's layer0 recurrent input
                A1[r*AS + h]      = hb;   // layer1 input, this step
            }
        }
        __syncthreads();
        // ---- phase 3: layer1 MFMA ----
        {
            bf16x8 a1[KS];
            #pragma unroll
            for (int ks = 0; ks < KS; ks++)
                a1[ks] = *(const bf16x8*)(A1 + n15*AS + ks*32 + q*8);
            #pragma unroll
            for (int j = 0; j < 3; j++) {
                f32x4 acc = { wb[3+j], wb[3+j], wb[3+j], wb[3+j] };
                #pragma unroll
                for (int ks = 0; ks < KS; ks++)
                    acc = __builtin_amdgcn_mfma_f32_16x16x32_bf16(a1[ks], wf[3+j][ks], acc, 0,0,0);
                const int base = (wave + 6*j)*16 + n15;
                #pragma unroll
                for (int r = 0; r < 4; r++) gates[(q*4+r)*GS + base] = acc[r];
            }
        }
        __syncthreads();
        // ---- phase 4: x(t+1) -> LDS, layer1 elementwise (c1 in regs) ----
        if (xl) {
            us4 s;
            #pragma unroll
            for (int e = 0; e < 4; e++) s[e] = f2bf(xn[e]);
            *(us4*)(A0 + xrow*AS + xcol) = s;
        }
        #pragma unroll
        for (int kk = 0; kk < 2; kk++) {
            const int u = tid + kk*NTHR;
            if (u < RB*HID) {
                const int r = u / HID, h = u - r*HID;
                const float* gr = gates + r*GS;
                float gi = gr[h], gf = gr[70+h], gg = gr[140+h], go = gr[210+h];
                float cn = sigm(gf)*c1[kk] + sigm(gi)*tanh_(gg);
                c1[kk] = cn;
                float hv = sigm(go)*tanh_(cn);
                A1[r*AS + 80 + h] = f2bf(hv);             // recurrent h1
                if (t == T_STEPS-1) h1f[r*HID + h] = hv;  // fp32 copy for head
            }
        }
        __syncthreads();
    }

    // ---- head: out = sigmoid(W2 @ relu(W1 @ h1 + b1) + b2) ----
    for (int uu = tid; uu < RB*50; uu += NTHR) {
        const int r = uu / 50, j = uu - r*50;
        float s = b1h[j];
        const float* w  = W1h + j*HID;
        const float* hh = h1f + r*HID;
        #pragma unroll 7
        for (int h = 0; h < HID; h++) s += w[h]*hh[h];
        mid[uu] = fmaxf(s, 0.0f);
    }
    __syncthreads();
    if (tid < RB) {
        float s = b2h[0];
        const float* m = mid + tid*50;
        #pragma unroll 10
        for (int j = 0; j < 50; j++) s += W2h[j]*m[j];
        out[blk*RB + tid] = sigm(s);
    }
}

extern "C" void kernel_launch(void* const* d_in, const int* in_sizes, int n_in,
                              void* d_out, int out_size, void* d_ws, size_t ws_size,
                              hipStream_t stream) {
    (void)in_sizes; (void)n_in; (void)out_size; (void)ws_size;
    const float* x    = (const float*)d_in[0];
    const float* Wih0 = (const float*)d_in[2];
    const float* Whh0 = (const float*)d_in[3];
    const float* bih0 = (const float*)d_in[4];
    const float* bhh0 = (const float*)d_in[5];
    const float* Wih1 = (const float*)d_in[6];
    const float* Whh1 = (const float*)d_in[7];
    const float* bih1 = (const float*)d_in[8];
    const float* bhh1 = (const float*)d_in[9];
    const float* W1h  = (const float*)d_in[10];
    const float* b1h  = (const float*)d_in[11];
    const float* W2h  = (const float*)d_in[12];
    const float* b2h  = (const float*)d_in[13];

    char* ws = (char*)d_ws;
    ushort_t* W0p  = (ushort_t*)ws;                       // 288*160 bf16 = 92160 B
    ushort_t* W1p  = (ushort_t*)(ws + 92160);             // 92160 B
    float*    bs0  = (float*)(ws + 184320);               // 288 f32
    float*    bs1  = (float*)(ws + 184320 + 1152);

    prep_kernel<<<180, 256, 0, stream>>>(Wih0, Whh0, bih0, bhh0,
                                         Wih1, Whh1, bih1, bhh1,
                                         W0p, W1p, bs0, bs1);
    lstm_kernel<<<BATCH/RB, NTHR, 0, stream>>>(x, W0p, W1p, bs0, bs1,
                                               W1h, b1h, W2h, b2h, (float*)d_out);
}

// Round 3
// 1512.222 us; speedup vs baseline: 1.4409x; 1.2870x over previous
//
#include <hip/hip_runtime.h>
#include <stdint.h>

#define T_STEPS 512
#define BATCH   4096
#define DIN     64
#define HID     70
#define KDIM    160      // padded K per layer (5 k-steps of 32)
#define KS      5
#define RB      16       // batch rows per block -> 256 blocks (1/CU)
#define WAVES   6
#define NTHR    (WAVES*64)
#define PROWS   384      // 24 n-tiles * 16 (gate j of h at col w*16+96*j+n15, h=6*n15+w)

typedef __bf16 bf16x8 __attribute__((ext_vector_type(8)));
typedef float  f32x4  __attribute__((ext_vector_type(4)));
typedef unsigned short ushort_t;
typedef ushort_t us4 __attribute__((ext_vector_type(4)));

__device__ __forceinline__ ushort_t f2bf(float f) {
    uint32_t u = __float_as_uint(f);
    u += 0x7fffu + ((u >> 16) & 1u);   // round-to-nearest-even
    return (ushort_t)(u >> 16);
}
__device__ __forceinline__ float sigm(float x) {
    return __builtin_amdgcn_rcpf(1.0f + __expf(-x));
}
__device__ __forceinline__ float tanh_(float x) {
    x = fminf(fmaxf(x, -15.f), 15.f);
    float r = __builtin_amdgcn_rcpf(1.0f + __expf(2.0f * x));
    return 1.0f - 2.0f * r;
}

// Gate-permuted padded bf16 weights, [384][160].
// Row p: nt=p>>4, n15=p&15, w=nt%6, j=nt/6, h=6*n15+w; torch gate row = j*70+h (h<70).
// k cols, layer0: k<64 -> W_ih0[g][k]; 64<=k<134 -> W_hh0[g][k-64]; else 0
//         layer1: k<70 -> W_ih1[g][k]; 80<=k<150 -> W_hh1[g][k-80]; else 0
__global__ void prep_kernel(const float* __restrict__ Wih0, const float* __restrict__ Whh0,
                            const float* __restrict__ bih0, const float* __restrict__ bhh0,
                            const float* __restrict__ Wih1, const float* __restrict__ Whh1,
                            const float* __restrict__ bih1, const float* __restrict__ bhh1,
                            ushort_t* __restrict__ W0p, ushort_t* __restrict__ W1p,
                            float* __restrict__ bsum0, float* __restrict__ bsum1) {
    int idx = blockIdx.x * 256 + threadIdx.x;
    const int n = PROWS * KDIM;
    if (idx < n) {
        int p = idx / KDIM, k = idx - p * KDIM;
        int nt = p >> 4, n15 = p & 15;
        int w = nt % 6, j = nt / 6;
        int h = 6 * n15 + w;
        float v0 = 0.f, v1 = 0.f;
        if (h < HID) {
            int g = j * HID + h;
            if (k < 64)        v0 = Wih0[g*64 + k];
            else if (k < 134)  v0 = Whh0[g*70 + (k-64)];
            if (k < 70)                  v1 = Wih1[g*70 + k];
            else if (k >= 80 && k < 150) v1 = Whh1[g*70 + (k-80)];
        }
        W0p[idx] = f2bf(v0);
        W1p[idx] = f2bf(v1);
    }
    if (idx < 280) {
        bsum0[idx] = bih0[idx] + bhh0[idx];
        bsum1[idx] = bih1[idx] + bhh1[idx];
    }
}

__global__ __launch_bounds__(NTHR, 2) void lstm_kernel(
    const float* __restrict__ x,              // [T][B][64] fp32
    const ushort_t* __restrict__ W0p, const ushort_t* __restrict__ W1p,
    const float* __restrict__ bsum0, const float* __restrict__ bsum1,
    const float* __restrict__ W1h, const float* __restrict__ b1h,
    const float* __restrict__ W2h, const float* __restrict__ b2h,
    float* __restrict__ out)
{
    constexpr int AS = 168;    // row stride (shorts) = 336 B (16B-aligned, non-pow2)
    // A0 cols: 0..63 x(t) | 64..133 h0(t-1) | pad ; A1 cols: 0..69 h0(t) | 80..149 h1(t-1) | pad
    __shared__ alignas(16) ushort_t A0[2][RB*AS];
    __shared__ alignas(16) ushort_t A1[2][RB*AS];
    __shared__ float h1f[RB*HID];
    __shared__ float mid[RB*50];

    const int tid  = threadIdx.x;
    const int wave = tid >> 6;
    const int lane = tid & 63;
    const int n15  = lane & 15;
    const int q    = lane >> 4;
    const int blk  = blockIdx.x;
    const int h    = 6*n15 + wave;          // this lane's hidden index (all 4 gates)
    const bool active = (h < HID);

    // Register-resident weight fragments: wave w owns tiles {w, w+6, w+12, w+18}.
    bf16x8 wf0[4][KS], wf1[4][KS];
    float  wb0[4], wb1[4];
    #pragma unroll
    for (int j = 0; j < 4; j++) {
        const int p = (wave + 6*j)*16 + n15;
        const int base = p*KDIM + q*8;
        #pragma unroll
        for (int ks = 0; ks < KS; ks++) {
            wf0[j][ks] = *(const bf16x8*)(W0p + base + ks*32);
            wf1[j][ks] = *(const bf16x8*)(W1p + base + ks*32);
        }
        wb0[j] = active ? bsum0[j*HID + h] : 0.f;
        wb1[j] = active ? bsum1[j*HID + h] : 0.f;
    }

    // zero both A-panel buffers (h(-1)=c(-1)=0, pads stay zero)
    for (int i = tid; i < RB*AS; i += NTHR) {
        A0[0][i] = 0; A0[1][i] = 0; A1[0][i] = 0; A1[1][i] = 0;
    }

    // x staging: threads 0..255 each own (row=tid>>4, col4=(tid&15)*4)
    const bool xl = (tid < 256);
    const int xrow = tid >> 4;
    const int xcol = (tid & 15) * 4;
    const float* xptr = x + ((size_t)blk*RB + xrow)*DIN + xcol;

    f32x4 xn;
    if (xl) xn = *(const f32x4*)xptr;     // x(0)
    __syncthreads();                       // zeros visible
    if (xl) {
        us4 s;
        #pragma unroll
        for (int e = 0; e < 4; e++) s[e] = f2bf(xn[e]);
        *(us4*)(&A0[0][xrow*AS + xcol]) = s;
    }
    __syncthreads();

    float c0[4] = {0,0,0,0}, c1[4] = {0,0,0,0};

    for (int t = 0; t < T_STEPS; t++) {
        const int cur = t & 1, nxt = cur ^ 1;
        // issue x(t+1) load early; LDS store happens in phase 2 (latency hidden)
        if (xl) {
            const int tn = (t+1 < T_STEPS) ? t+1 : t;
            xn = *(const f32x4*)(xptr + (size_t)tn * (BATCH*DIN));
        }
        // ---- phase 1: layer0 MFMA (gates land in registers) ----
        {
            bf16x8 a[KS];
            #pragma unroll
            for (int ks = 0; ks < KS; ks++)
                a[ks] = *(const bf16x8*)(&A0[cur][n15*AS + ks*32 + q*8]);
            f32x4 gi = {wb0[0],wb0[0],wb0[0],wb0[0]};
            f32x4 gf = {wb0[1],wb0[1],wb0[1],wb0[1]};
            f32x4 gg = {wb0[2],wb0[2],wb0[2],wb0[2]};
            f32x4 go = {wb0[3],wb0[3],wb0[3],wb0[3]};
            #pragma unroll
            for (int ks = 0; ks < KS; ks++) {
                gi = __builtin_amdgcn_mfma_f32_16x16x32_bf16(a[ks], wf0[0][ks], gi, 0,0,0);
                gf = __builtin_amdgcn_mfma_f32_16x16x32_bf16(a[ks], wf0[1][ks], gf, 0,0,0);
                gg = __builtin_amdgcn_mfma_f32_16x16x32_bf16(a[ks], wf0[2][ks], gg, 0,0,0);
                go = __builtin_amdgcn_mfma_f32_16x16x32_bf16(a[ks], wf0[3][ks], go, 0,0,0);
            }
            if (active) {
                #pragma unroll
                for (int r = 0; r < 4; r++) {
                    float i_ = sigm(gi[r]), f_ = sigm(gf[r]);
                    float g_ = tanh_(gg[r]), o_ = sigm(go[r]);
                    float cn = f_*c0[r] + i_*g_;
                    c0[r] = cn;
                    ushort_t hb = f2bf(o_*tanh_(cn));
                    const int row = q*4 + r;
                    A0[nxt][row*AS + 64 + h] = hb;   // next step's L0 recurrent
                    A1[cur][row*AS + h]      = hb;   // this step's L1 input
                }
            }
        }
        __syncthreads();
        // ---- phase 2: layer1 MFMA + elementwise; x(t+1) -> other buffer ----
        {
            bf16x8 a[KS];
            #pragma unroll
            for (int ks = 0; ks < KS; ks++)
                a[ks] = *(const bf16x8*)(&A1[cur][n15*AS + ks*32 + q*8]);
            f32x4 gi = {wb1[0],wb1[0],wb1[0],wb1[0]};
            f32x4 gf = {wb1[1],wb1[1],wb1[1],wb1[1]};
            f32x4 gg = {wb1[2],wb1[2],wb1[2],wb1[2]};
            f32x4 go = {wb1[3],wb1[3],wb1[3],wb1[3]};
            #pragma unroll
            for (int ks = 0; ks < KS; ks++) {
                gi = __builtin_amdgcn_mfma_f32_16x16x32_bf16(a[ks], wf1[0][ks], gi, 0,0,0);
                gf = __builtin_amdgcn_mfma_f32_16x16x32_bf16(a[ks], wf1[1][ks], gf, 0,0,0);
                gg = __builtin_amdgcn_mfma_f32_16x16x32_bf16(a[ks], wf1[2][ks], gg, 0,0,0);
                go = __builtin_amdgcn_mfma_f32_16x16x32_bf16(a[ks], wf1[3][ks], go, 0,0,0);
            }
            if (xl) {
                us4 s;
                #pragma unroll
                for (int e = 0; e < 4; e++) s[e] = f2bf(xn[e]);
                *(us4*)(&A0[nxt][xrow*AS + xcol]) = s;
            }
            if (active) {
                #pragma unroll
                for (int r = 0; r < 4; r++) {
                    float i_ = sigm(gi[r]), f_ = sigm(gf[r]);
                    float g_ = tanh_(gg[r]), o_ = sigm(go[r]);
                    float cn = f_*c1[r] + i_*g_;
                    c1[r] = cn;
                    float hv = o_*tanh_(cn);
                    const int row = q*4 + r;
                    A1[nxt][row*AS + 80 + h] = f2bf(hv);      // recurrent h1
                    if (t == T_STEPS-1) h1f[row*HID + h] = hv;
                }
            }
        }
        __syncthreads();
    }

    // ---- head: out = sigmoid(W2 @ relu(W1 @ h1 + b1) + b2) ----
    for (int uu = tid; uu < RB*50; uu += NTHR) {
        const int r = uu / 50, j = uu - r*50;
        float s = b1h[j];
        const float* wgt = W1h + j*HID;
        const float* hh  = h1f + r*HID;
        #pragma unroll 7
        for (int k = 0; k < HID; k++) s += wgt[k]*hh[k];
        mid[uu] = fmaxf(s, 0.0f);
    }
    __syncthreads();
    if (tid < RB) {
        float s = b2h[0];
        const float* m = mid + tid*50;
        #pragma unroll 10
        for (int j = 0; j < 50; j++) s += W2h[j]*m[j];
        out[blk*RB + tid] = sigm(s);
    }
}

extern "C" void kernel_launch(void* const* d_in, const int* in_sizes, int n_in,
                              void* d_out, int out_size, void* d_ws, size_t ws_size,
                              hipStream_t stream) {
    (void)in_sizes; (void)n_in; (void)out_size; (void)ws_size;
    const float* x    = (const float*)d_in[0];
    const float* Wih0 = (const float*)d_in[2];
    const float* Whh0 = (const float*)d_in[3];
    const float* bih0 = (const float*)d_in[4];
    const float* bhh0 = (const float*)d_in[5];
    const float* Wih1 = (const float*)d_in[6];
    const float* Whh1 = (const float*)d_in[7];
    const float* bih1 = (const float*)d_in[8];
    const float* bhh1 = (const float*)d_in[9];
    const float* W1h  = (const float*)d_in[10];
    const float* b1h  = (const float*)d_in[11];
    const float* W2h  = (const float*)d_in[12];
    const float* b2h  = (const float*)d_in[13];

    char* ws = (char*)d_ws;
    ushort_t* W0p  = (ushort_t*)ws;                       // 384*160 bf16 = 122880 B
    ushort_t* W1p  = (ushort_t*)(ws + 122880);            // 122880 B
    float*    bs0  = (float*)(ws + 245760);               // 280 f32
    float*    bs1  = (float*)(ws + 245760 + 1120);

    prep_kernel<<<240, 256, 0, stream>>>(Wih0, Whh0, bih0, bhh0,
                                         Wih1, Whh1, bih1, bhh1,
                                         W0p, W1p, bs0, bs1);
    lstm_kernel<<<BATCH/RB, NTHR, 0, stream>>>(x, W0p, W1p, bs0, bs1,
                                               W1h, b1h, W2h, b2h, (float*)d_out);
}

// Round 4
// 1286.180 us; speedup vs baseline: 1.6941x; 1.1757x over previous
//
#include <hip/hip_runtime.h>
#include <stdint.h>

#define T_STEPS 512
#define BATCH   4096
#define DIN     64
#define HID     70
#define KDIM    160      // padded K per layer (5 k-steps of 32)
#define KS      5
#define RB      16       // batch rows per block -> 256 blocks (1/CU)
#define WAVES   12       // 0..5 layer1, 6..11 layer0  (3 waves/SIMD, balanced)
#define NTHR    (WAVES*64)
#define PROWS   384      // 24 n-tiles: gate j of h at tile 6j+w, h=6*n15+w

typedef __bf16 bf16x8 __attribute__((ext_vector_type(8)));
typedef float  f32x4  __attribute__((ext_vector_type(4)));
typedef unsigned short ushort_t;
typedef ushort_t us4 __attribute__((ext_vector_type(4)));

__device__ __forceinline__ ushort_t f2bf(float f) {
    uint32_t u = __float_as_uint(f);
    u += 0x7fffu + ((u >> 16) & 1u);   // round-to-nearest-even
    return (ushort_t)(u >> 16);
}
__device__ __forceinline__ float sigm(float x) {
    return __builtin_amdgcn_rcpf(1.0f + __expf(-x));
}
// no clamp needed: exp->inf => rcp->0 => 1; exp->0 => 1-2 = -1 (exact limits)
__device__ __forceinline__ float tanh_(float x) {
    float r = __builtin_amdgcn_rcpf(1.0f + __expf(2.0f * x));
    return 1.0f - 2.0f * r;
}

// Gate-permuted padded bf16 weights, [384][160].
// Row p: nt=p>>4, n15=p&15, w=nt%6, j=nt/6, h=6*n15+w; torch gate row = j*70+h (h<70).
// k cols, layer0: k<64 -> W_ih0[g][k]; 64<=k<134 -> W_hh0[g][k-64]; else 0
//         layer1: k<70 -> W_ih1[g][k]; 80<=k<150 -> W_hh1[g][k-80]; else 0
__global__ void prep_kernel(const float* __restrict__ Wih0, const float* __restrict__ Whh0,
                            const float* __restrict__ bih0, const float* __restrict__ bhh0,
                            const float* __restrict__ Wih1, const float* __restrict__ Whh1,
                            const float* __restrict__ bih1, const float* __restrict__ bhh1,
                            ushort_t* __restrict__ W0p, ushort_t* __restrict__ W1p,
                            float* __restrict__ bsum0, float* __restrict__ bsum1) {
    int idx = blockIdx.x * 256 + threadIdx.x;
    const int n = PROWS * KDIM;
    if (idx < n) {
        int p = idx / KDIM, k = idx - p * KDIM;
        int nt = p >> 4, n15 = p & 15;
        int w = nt % 6, j = nt / 6;
        int h = 6 * n15 + w;
        float v0 = 0.f, v1 = 0.f;
        if (h < HID) {
            int g = j * HID + h;
            if (k < 64)        v0 = Wih0[g*64 + k];
            else if (k < 134)  v0 = Whh0[g*70 + (k-64)];
            if (k < 70)                  v1 = Wih1[g*70 + k];
            else if (k >= 80 && k < 150) v1 = Whh1[g*70 + (k-80)];
        }
        W0p[idx] = f2bf(v0);
        W1p[idx] = f2bf(v1);
    }
    if (idx < 280) {
        bsum0[idx] = bih0[idx] + bhh0[idx];
        bsum1[idx] = bih1[idx] + bhh1[idx];
    }
}

__global__ __launch_bounds__(NTHR) void lstm_kernel(
    const float* __restrict__ x,              // [T][B][64] fp32
    const ushort_t* __restrict__ W0p, const ushort_t* __restrict__ W1p,
    const float* __restrict__ bsum0, const float* __restrict__ bsum1,
    const float* __restrict__ W1h, const float* __restrict__ b1h,
    const float* __restrict__ W2h, const float* __restrict__ b2h,
    float* __restrict__ out)
{
    constexpr int AS = 168;    // row stride (shorts) = 336 B
    // A0 cols: 0..63 x(p+1) | 64..133 h0(p) | pad     (L0 computes step p+1)
    // A1 cols: 0..69 h0(p)  | 80..149 h1(p-1) | pad   (L1 computes step p)
    __shared__ alignas(16) ushort_t A0[2][RB*AS];
    __shared__ alignas(16) ushort_t A1[2][RB*AS];
    __shared__ float h1f[RB*HID];
    __shared__ float mid[RB*50];

    const int tid  = threadIdx.x;
    const int wave = tid >> 6;
    const int lane = tid & 63;
    const int n15  = lane & 15;
    const int q    = lane >> 4;
    const int blk  = blockIdx.x;
    const bool isL0 = (wave >= 6);
    const int lw   = isL0 ? wave - 6 : wave;   // tile-set index within layer
    const int h    = 6*n15 + lw;               // this lane's hidden index (all 4 gates)
    const bool active = (h < HID);

    // Register-resident weights: each wave holds ONE layer's 4 gate-tiles.
    const ushort_t* __restrict__ Wp = isL0 ? W0p : W1p;
    const float*    __restrict__ bs = isL0 ? bsum0 : bsum1;
    bf16x8 wf[4][KS];
    float  wb[4];
    #pragma unroll
    for (int j = 0; j < 4; j++) {
        const int base = ((lw + 6*j)*16 + n15)*KDIM + q*8;
        #pragma unroll
        for (int ks = 0; ks < KS; ks++)
            wf[j][ks] = *(const bf16x8*)(Wp + base + ks*32);
        wb[j] = active ? bs[j*HID + h] : 0.f;
    }

    // zero all panels (h(-1)=0, pads stay zero forever)
    for (int i = tid; i < RB*AS; i += NTHR) {
        A0[0][i] = 0; A0[1][i] = 0; A1[0][i] = 0; A1[1][i] = 0;
    }

    // x staging: threads 384..639 (L0 waves 6..9), one f32x4 each
    const int  xt   = tid - 384;
    const bool xl   = (xt >= 0) && (xt < 256);
    const int  xrow = xt >> 4;
    const int  xcol = (xt & 15) * 4;
    const float* xptr = x + ((size_t)blk*RB + xrow)*DIN + xcol;

    f32x4 x0v, x1v, xcur;
    if (xl) {
        x0v  = *(const f32x4*)(xptr);
        x1v  = *(const f32x4*)(xptr + (size_t)1*(BATCH*DIN));
        xcur = *(const f32x4*)(xptr + (size_t)2*(BATCH*DIN));
    }
    __syncthreads();                 // zeros visible
    if (xl) {
        us4 s0, s1;
        #pragma unroll
        for (int e = 0; e < 4; e++) { s0[e] = f2bf(x0v[e]); s1[e] = f2bf(x1v[e]); }
        *(us4*)(&A0[1][xrow*AS + xcol]) = s0;   // x(0) -> prologue panel
        *(us4*)(&A0[0][xrow*AS + xcol]) = s1;   // x(1) -> phase-0 panel
    }
    __syncthreads();

    float cc[4] = {0,0,0,0};         // c0 (L0 waves) or c1 (L1 waves)

    // ---- prologue: L0 step 0 from A0[1] = [x(0), h0(-1)=0] ----
    if (isL0) {
        bf16x8 a[KS];
        #pragma unroll
        for (int ks = 0; ks < KS; ks++)
            a[ks] = *(const bf16x8*)(&A0[1][n15*AS + ks*32 + q*8]);
        f32x4 gi = {wb[0],wb[0],wb[0],wb[0]};
        f32x4 gf = {wb[1],wb[1],wb[1],wb[1]};
        f32x4 gg = {wb[2],wb[2],wb[2],wb[2]};
        f32x4 go = {wb[3],wb[3],wb[3],wb[3]};
        #pragma unroll
        for (int ks = 0; ks < KS; ks++) {
            gi = __builtin_amdgcn_mfma_f32_16x16x32_bf16(a[ks], wf[0][ks], gi, 0,0,0);
            gf = __builtin_amdgcn_mfma_f32_16x16x32_bf16(a[ks], wf[1][ks], gf, 0,0,0);
            gg = __builtin_amdgcn_mfma_f32_16x16x32_bf16(a[ks], wf[2][ks], gg, 0,0,0);
            go = __builtin_amdgcn_mfma_f32_16x16x32_bf16(a[ks], wf[3][ks], go, 0,0,0);
        }
        if (active) {
            #pragma unroll
            for (int r = 0; r < 4; r++) {
                float i_ = sigm(gi[r]), f_ = sigm(gf[r]);
                float g_ = tanh_(gg[r]), o_ = sigm(go[r]);
                float cn = f_*cc[r] + i_*g_;
                cc[r] = cn;
                ushort_t hb = f2bf(o_*tanh_(cn));
                const int row = q*4 + r;
                A1[0][row*AS + h]      = hb;   // L1 input h0(0)
                A0[0][row*AS + 64 + h] = hb;   // L0 recurrent h0(0)
            }
        }
    }
    __syncthreads();

    // ---- main loop: phase p computes L1 step p  and  L0 step p+1 ----
    for (int p = 0; p < T_STEPS; p++) {
        const int cur = p & 1, nxt = cur ^ 1;
        f32x4 xn;
        if (xl) {
            const int tn = (p+3 < T_STEPS) ? p+3 : T_STEPS-1;
            xn = *(const f32x4*)(xptr + (size_t)tn*(BATCH*DIN));
        }
        const ushort_t* __restrict__ Apan = isL0 ? &A0[cur][0] : &A1[cur][0];
        bf16x8 a[KS];
        #pragma unroll
        for (int ks = 0; ks < KS; ks++)
            a[ks] = *(const bf16x8*)(Apan + n15*AS + ks*32 + q*8);
        f32x4 gi = {wb[0],wb[0],wb[0],wb[0]};
        f32x4 gf = {wb[1],wb[1],wb[1],wb[1]};
        f32x4 gg = {wb[2],wb[2],wb[2],wb[2]};
        f32x4 go = {wb[3],wb[3],wb[3],wb[3]};
        #pragma unroll
        for (int ks = 0; ks < KS; ks++) {
            gi = __builtin_amdgcn_mfma_f32_16x16x32_bf16(a[ks], wf[0][ks], gi, 0,0,0);
            gf = __builtin_amdgcn_mfma_f32_16x16x32_bf16(a[ks], wf[1][ks], gf, 0,0,0);
            gg = __builtin_amdgcn_mfma_f32_16x16x32_bf16(a[ks], wf[2][ks], gg, 0,0,0);
            go = __builtin_amdgcn_mfma_f32_16x16x32_bf16(a[ks], wf[3][ks], go, 0,0,0);
        }
        if (xl) {   // store x(p+2) into next L0 panel (loaded last phase; long since arrived)
            us4 s;
            #pragma unroll
            for (int e = 0; e < 4; e++) s[e] = f2bf(xcur[e]);
            *(us4*)(&A0[nxt][xrow*AS + xcol]) = s;
        }
        if (active) {
            #pragma unroll
            for (int r = 0; r < 4; r++) {
                float i_ = sigm(gi[r]), f_ = sigm(gf[r]);
                float g_ = tanh_(gg[r]), o_ = sigm(go[r]);
                float cn = f_*cc[r] + i_*g_;
                cc[r] = cn;
                float hv = o_*tanh_(cn);
                const int row = q*4 + r;
                if (isL0) {                    // h0(p+1)
                    ushort_t hb = f2bf(hv);
                    A1[nxt][row*AS + h]      = hb;
                    A0[nxt][row*AS + 64 + h] = hb;
                } else {                       // h1(p)
                    A1[nxt][row*AS + 80 + h] = f2bf(hv);
                    if (p == T_STEPS-1) h1f[row*HID + h] = hv;
                }
            }
        }
        if (xl) xcur = xn;
        __syncthreads();
    }

    // ---- head: out = sigmoid(W2 @ relu(W1 @ h1 + b1) + b2) ----
    for (int uu = tid; uu < RB*50; uu += NTHR) {
        const int r = uu / 50, j = uu - r*50;
        float s = b1h[j];
        const float* wgt = W1h + j*HID;
        const float* hh  = h1f + r*HID;
        #pragma unroll 7
        for (int k = 0; k < HID; k++) s += wgt[k]*hh[k];
        mid[uu] = fmaxf(s, 0.0f);
    }
    __syncthreads();
    if (tid < RB) {
        float s = b2h[0];
        const float* m = mid + tid*50;
        #pragma unroll 10
        for (int j = 0; j < 50; j++) s += W2h[j]*m[j];
        out[blk*RB + tid] = sigm(s);
    }
}

extern "C" void kernel_launch(void* const* d_in, const int* in_sizes, int n_in,
                              void* d_out, int out_size, void* d_ws, size_t ws_size,
                              hipStream_t stream) {
    (void)in_sizes; (void)n_in; (void)out_size; (void)ws_size;
    const float* x    = (const float*)d_in[0];
    const float* Wih0 = (const float*)d_in[2];
    const float* Whh0 = (const float*)d_in[3];
    const float* bih0 = (const float*)d_in[4];
    const float* bhh0 = (const float*)d_in[5];
    const float* Wih1 = (const float*)d_in[6];
    const float* Whh1 = (const float*)d_in[7];
    const float* bih1 = (const float*)d_in[8];
    const float* bhh1 = (const float*)d_in[9];
    const float* W1h  = (const float*)d_in[10];
    const float* b1h  = (const float*)d_in[11];
    const float* W2h  = (const float*)d_in[12];
    const float* b2h  = (const float*)d_in[13];

    char* ws = (char*)d_ws;
    ushort_t* W0p  = (ushort_t*)ws;                       // 384*160 bf16 = 122880 B
    ushort_t* W1p  = (ushort_t*)(ws + 122880);            // 122880 B
    float*    bs0  = (float*)(ws + 245760);               // 280 f32
    float*    bs1  = (float*)(ws + 245760 + 1120);

    prep_kernel<<<240, 256, 0, stream>>>(Wih0, Whh0, bih0, bhh0,
                                         Wih1, Whh1, bih1, bhh1,
                                         W0p, W1p, bs0, bs1);
    lstm_kernel<<<BATCH/RB, NTHR, 0, stream>>>(x, W0p, W1p, bs0, bs1,
                                               W1h, b1h, W2h, b2h, (float*)d_out);
}